// Round 1
// baseline (436.872 us; speedup 1.0000x reference)
//
#include <hip/hip_runtime.h>
#include <hip/hip_bf16.h>

// ---------------------------------------------------------------------------
// MoE dense all-expert forward, MI355X / gfx950.
//   B=16384, D=H=O=256, E=32, top-k=22, TEMP=e.
// Plan:
//   k0: f32 -> bf16 convert (x, W1, W2) into workspace
//   k1: gating: scores(f32) -> softmax -> top-22 -> renorm weights (ws)
//       also writes bias2[b,o] = sum_e w[b,e]*b2[e,o] into d_out (acc init)
//   k2: fused MoE: per 64-row block, loop 32 experts:
//       GEMM1 (MFMA bf16 16x16x32, x from LDS, W1 from global)
//       -> +b1, relu, *gate weight, bf16 -> LDS (swizzled)
//       GEMM2 accumulate into persistent f32 out tile (init = bias2)
// ---------------------------------------------------------------------------

typedef __attribute__((ext_vector_type(8))) short bf16x8;   // 8 bf16 = 4 VGPRs
typedef __attribute__((ext_vector_type(4))) float f32x4;

__device__ __forceinline__ unsigned short f2bf(float f) {
    unsigned u = __builtin_bit_cast(unsigned, f);
    u += 0x7FFFu + ((u >> 16) & 1u);        // round-to-nearest-even
    return (unsigned short)(u >> 16);
}

// --------------------------- f32 -> bf16 convert ---------------------------
__global__ __launch_bounds__(256) void cvt_bf16(const float* __restrict__ src,
                                                unsigned short* __restrict__ dst,
                                                int n4) {
    int i = blockIdx.x * 256 + threadIdx.x;
    if (i < n4) {
        float4 v = ((const float4*)src)[i];
        ushort4 o;
        o.x = f2bf(v.x); o.y = f2bf(v.y); o.z = f2bf(v.z); o.w = f2bf(v.w);
        ((ushort4*)dst)[i] = o;
    }
}

// ------------------------------- gating ------------------------------------
// 4 waves/block, one row per wave. All in f32 to match reference selection.
__global__ __launch_bounds__(256) void gating_kernel(
    const float* __restrict__ x, const float* __restrict__ Wg,
    const float* __restrict__ bg, const float* __restrict__ b2,
    float* __restrict__ wout, float* __restrict__ out)
{
    __shared__ float xrow[4][256];
    const int wave = threadIdx.x >> 6, lane = threadIdx.x & 63;
    const int row = blockIdx.x * 4 + wave;

    ((float4*)xrow[wave])[lane] = ((const float4*)(x + (long)row * 256))[lane];
    __syncthreads();

    const int e = lane & 31, half = lane >> 5;
    const float4* wg4 = (const float4*)(Wg + e * 256 + half * 128);
    const float4* xr4 = (const float4*)(&xrow[wave][half * 128]);
    float acc = 0.f;
#pragma unroll
    for (int i = 0; i < 32; ++i) {
        float4 w = wg4[i], xv = xr4[i];
        acc = fmaf(w.x, xv.x, acc); acc = fmaf(w.y, xv.y, acc);
        acc = fmaf(w.z, xv.z, acc); acc = fmaf(w.w, xv.w, acc);
    }
    acc += __shfl_xor(acc, 32);
    float score = (acc + bg[e]) / 2.71828182845904523f;   // TEMP = e

    float m = score;
#pragma unroll
    for (int d = 16; d >= 1; d >>= 1) m = fmaxf(m, __shfl_xor(m, d));
    float p = expf(score - m);
    float ps = p;
#pragma unroll
    for (int d = 16; d >= 1; d >>= 1) ps += __shfl_xor(ps, d);
    float prob = p / ps;

    int rank = 0;
#pragma unroll
    for (int j = 0; j < 32; ++j) {
        float pj = __shfl(prob, j);
        rank += (pj > prob || (pj == prob && j < e)) ? 1 : 0;
    }
    float kept = (rank < 22) ? prob : 0.f;
    float wsum = kept;
#pragma unroll
    for (int d = 16; d >= 1; d >>= 1) wsum += __shfl_xor(wsum, d);
    float weight = kept / (wsum + 1e-8f);

    if (half == 0) wout[(long)row * 32 + e] = weight;

    // bias2 row: sum_e w_e * b2[e,:]  -> d_out (accumulator init for k2)
    float4 a4 = {0.f, 0.f, 0.f, 0.f};
#pragma unroll
    for (int j = 0; j < 32; ++j) {
        float wj = __shfl(weight, j);
        float4 bv = ((const float4*)(b2 + j * 256))[lane];
        a4.x = fmaf(wj, bv.x, a4.x); a4.y = fmaf(wj, bv.y, a4.y);
        a4.z = fmaf(wj, bv.z, a4.z); a4.w = fmaf(wj, bv.w, a4.w);
    }
    ((float4*)(out + (long)row * 256))[lane] = a4;
}

// ------------------------------ fused MoE ----------------------------------
// 256 blocks x 512 threads (8 waves). Block = 64 batch rows x all 256 outs.
// Wave w owns N-columns [w*32, w*32+32). LDS x/h tiles 32 KB each (flat 256
// stride, 16B-chunk XOR swizzle by (row&7) -> conflict-free b128 reads).
#define LDS_CHUNK_ADDR(r, chunk) (((r) * 256) + ((((chunk)) ^ ((r) & 7)) * 8))

__global__ __launch_bounds__(512, 2) void moe_kernel(
    const unsigned short* __restrict__ xb,
    const unsigned short* __restrict__ W1b,
    const unsigned short* __restrict__ W2b,
    const float* __restrict__ b1,
    const float* __restrict__ wgt,
    float* __restrict__ out)
{
    __shared__ __align__(16) unsigned short x_s[64 * 256];
    __shared__ __align__(16) unsigned short h_s[64 * 256];

    const int tid  = threadIdx.x;
    const int wv   = tid >> 6, lane = tid & 63;
    const int quad = lane >> 4, l15 = lane & 15;
    const int row0 = blockIdx.x * 64;
    const int nbase = wv * 32;

    // stage x tile (64 rows x 512B), swizzled
#pragma unroll
    for (int c = 0; c < 4; ++c) {
        int chunk = tid + c * 512;            // 2048 x 16B
        int r = chunk >> 5, c16 = chunk & 31;
        uint4 v = *(const uint4*)(xb + (long)(row0 + r) * 256 + c16 * 8);
        *(uint4*)(&x_s[LDS_CHUNK_ADDR(r, c16)]) = v;
    }

    // out accumulator init = bias2 tile written by gating kernel
    f32x4 oacc[4][2];
#pragma unroll
    for (int mt = 0; mt < 4; ++mt)
#pragma unroll
        for (int nt = 0; nt < 2; ++nt)
#pragma unroll
            for (int r = 0; r < 4; ++r)
                oacc[mt][nt][r] =
                    out[(long)(row0 + mt * 16 + quad * 4 + r) * 256 + nbase + nt * 16 + l15];

    __syncthreads();

    const unsigned short* w1p = W1b + (long)(nbase + l15) * 256 + quad * 8;
    const unsigned short* w2p = W2b + (long)(nbase + l15) * 256 + quad * 8;

#pragma unroll 1
    for (int e = 0; e < 32; ++e) {
        f32x4 hacc[4][2];
#pragma unroll
        for (int mt = 0; mt < 4; ++mt)
#pragma unroll
            for (int nt = 0; nt < 2; ++nt) {
                f32x4 z = {0.f, 0.f, 0.f, 0.f};
                hacc[mt][nt] = z;
            }

        // ---- GEMM1: h = x @ W1[e]^T  (reads x_s + global W1) ----
        const unsigned short* w1e = w1p + e * 65536;
#pragma unroll
        for (int k = 0; k < 8; ++k) {
            bf16x8 a[4], b[2];
#pragma unroll
            for (int mt = 0; mt < 4; ++mt)
                a[mt] = *(const bf16x8*)(&x_s[LDS_CHUNK_ADDR(mt * 16 + l15, k * 4 + quad)]);
#pragma unroll
            for (int nt = 0; nt < 2; ++nt)
                b[nt] = *(const bf16x8*)(w1e + nt * 16 * 256 + k * 32);
#pragma unroll
            for (int mt = 0; mt < 4; ++mt)
#pragma unroll
                for (int nt = 0; nt < 2; ++nt)
                    hacc[mt][nt] = __builtin_amdgcn_mfma_f32_16x16x32_bf16(
                        a[mt], b[nt], hacc[mt][nt], 0, 0, 0);
        }

        __syncthreads();   // previous expert's GEMM2 done reading h_s

        // ---- epilogue: +b1, relu, * gate weight, -> h_s (bf16) ----
#pragma unroll
        for (int nt = 0; nt < 2; ++nt) {
            int col = nbase + nt * 16 + l15;
            float b1v = b1[e * 256 + col];
#pragma unroll
            for (int mt = 0; mt < 4; ++mt)
#pragma unroll
                for (int r = 0; r < 4; ++r) {
                    int rl = mt * 16 + quad * 4 + r;
                    float gw = wgt[(long)(row0 + rl) * 32 + e];   // L1-hot broadcast
                    float v = hacc[mt][nt][r] + b1v;
                    v = fmaxf(v, 0.f) * gw;
                    h_s[LDS_CHUNK_ADDR(rl, col >> 3) + (col & 7)] = f2bf(v);
                }
        }

        __syncthreads();   // h_s ready

        // ---- GEMM2: out += h @ W2[e]^T ----
        const unsigned short* w2e = w2p + e * 65536;
#pragma unroll
        for (int k = 0; k < 8; ++k) {
            bf16x8 a[4], b[2];
#pragma unroll
            for (int mt = 0; mt < 4; ++mt)
                a[mt] = *(const bf16x8*)(&h_s[LDS_CHUNK_ADDR(mt * 16 + l15, k * 4 + quad)]);
#pragma unroll
            for (int nt = 0; nt < 2; ++nt)
                b[nt] = *(const bf16x8*)(w2e + nt * 16 * 256 + k * 32);
#pragma unroll
            for (int mt = 0; mt < 4; ++mt)
#pragma unroll
                for (int nt = 0; nt < 2; ++nt)
                    oacc[mt][nt] = __builtin_amdgcn_mfma_f32_16x16x32_bf16(
                        a[mt], b[nt], oacc[mt][nt], 0, 0, 0);
        }
    }

    // final store
#pragma unroll
    for (int mt = 0; mt < 4; ++mt)
#pragma unroll
        for (int nt = 0; nt < 2; ++nt)
#pragma unroll
            for (int r = 0; r < 4; ++r)
                out[(long)(row0 + mt * 16 + quad * 4 + r) * 256 + nbase + nt * 16 + l15] =
                    oacc[mt][nt][r];
}

// ------------------------------- launch ------------------------------------
extern "C" void kernel_launch(void* const* d_in, const int* in_sizes, int n_in,
                              void* d_out, int out_size, void* d_ws, size_t ws_size,
                              hipStream_t stream) {
    (void)in_sizes; (void)n_in; (void)out_size; (void)ws_size;
    const float* x  = (const float*)d_in[0];   // [16384,256]
    const float* W1 = (const float*)d_in[1];   // [32,256,256]
    const float* b1 = (const float*)d_in[2];   // [32,256]
    const float* W2 = (const float*)d_in[3];   // [32,256,256]
    const float* b2 = (const float*)d_in[4];   // [32,256]
    const float* Wg = (const float*)d_in[5];   // [32,256]
    const float* bg = (const float*)d_in[6];   // [32]
    float* out = (float*)d_out;                // [16384,256]

    char* ws = (char*)d_ws;
    float*          wgt = (float*)ws;                                  // 2 MB
    unsigned short* xb  = (unsigned short*)(ws + (2u  << 20));         // 8 MB
    unsigned short* W1b = (unsigned short*)(ws + (10u << 20));         // 4 MB
    unsigned short* W2b = (unsigned short*)(ws + (14u << 20));         // 4 MB

    cvt_bf16<<<4096, 256, 0, stream>>>(x,  xb,  16384 * 256 / 4);
    cvt_bf16<<<2048, 256, 0, stream>>>(W1, W1b, 32 * 256 * 256 / 4);
    cvt_bf16<<<2048, 256, 0, stream>>>(W2, W2b, 32 * 256 * 256 / 4);
    gating_kernel<<<4096, 256, 0, stream>>>(x, Wg, bg, b2, wgt, out);
    moe_kernel<<<256, 512, 0, stream>>>(xb, W1b, W2b, b1, wgt, out);
}